// Round 11
// baseline (342.255 us; speedup 1.0000x reference)
//
#include <hip/hip_runtime.h>
#include <hip/hip_bf16.h>

#define N_NODES 100000
#define N_EDGES 1600000
#define F_IN 128
#define HID 64
#define N_GRAPHS 1024

// fine dst-partition: bucket = dst>>9 (512 nodes/bucket)
#define SH 9
#define NBU 196        // buckets used: ceil(100000/512)
#define NB 200         // allocated
#define BCAP 9728      // mean 8192 + 17 sigma
#define EPB 2048       // edges per k_part block (782 blocks, ~3/CU)
#define NSLICE 2       // gemm1 output: 2 slices x 32 feats (64-B rows)

typedef __attribute__((ext_vector_type(8))) short bf16x8;
typedef __attribute__((ext_vector_type(4))) float f32x4;
typedef __attribute__((ext_vector_type(4))) unsigned int u32x4;

// ---------------- bf16 bit helpers --------------------------------------------
__device__ __forceinline__ unsigned short f2bf(float f) {
    __hip_bfloat16 h = __float2bfloat16(f);   // RNE
    return *reinterpret_cast<unsigned short*>(&h);
}
__device__ __forceinline__ float bf2f(unsigned int u) {
    return __uint_as_float(u << 16);
}

// ---------------- dual-path load helpers (wire dtype resolved at runtime) -----
__device__ __forceinline__ float loadf(const void* p, size_t i, int f32) {
    if (f32) return ((const float*)p)[i];
    return __bfloat162float(((const __hip_bfloat16*)p)[i]);
}
__device__ __forceinline__ int loadi(const void* p, size_t i, int i64) {
    if (i64) return (int)((const long long*)p)[i];
    return ((const int*)p)[i];
}

// ---------------- init: wire detect + zero small counters ---------------------
__global__ void k_init(const unsigned int* __restrict__ xw_,
                       const unsigned int* __restrict__ ei_,
                       int* __restrict__ flags,
                       int* __restrict__ gcnt, int* __restrict__ bcnt) {
    __shared__ int cnt_f, cnt_i;
    int t = threadIdx.x;
    if (t == 0) { cnt_f = 0; cnt_i = 0; }
    __syncthreads();
    unsigned int w = xw_[t];
    unsigned int e = (w >> 7) & 0xFFu;
    if (e >= 100u && e <= 140u) atomicAdd(&cnt_f, 1);
    unsigned int iw = ei_[2 * t + 1];
    if (iw == 0u) atomicAdd(&cnt_i, 1);
    for (int i = t; i < N_GRAPHS; i += 256) gcnt[i] = 0;
    for (int i = t; i < NB; i += 256) bcnt[i] = 0;
    __syncthreads();
    if (t == 0) {
        flags[0] = (cnt_f < 180) ? 1 : 0;   // 1 => fp32 wire
        flags[1] = (cnt_i >= 128) ? 1 : 0;  // 1 => int64 wire
    }
}

// ---------------- phase A: partition by dst>>9, two-pass blocks ---------------
__global__ __launch_bounds__(256) void k_part(const void* __restrict__ ei,
                                              const void* __restrict__ batch,
                                              int* __restrict__ bcnt,
                                              int* __restrict__ gcnt,
                                              unsigned int* __restrict__ packed,
                                              const int* __restrict__ flags) {
    int I64 = flags[1];
    __shared__ int hist[NB];
    __shared__ int base[NB];
    __shared__ int ghist[N_GRAPHS];        // 4 KB
    __shared__ unsigned int elds[EPB];     // 8 KB: packed words
    __shared__ unsigned char ebkt[EPB];    // 2 KB: bucket ids (0xFF = invalid)
    int t = threadIdx.x;
    if (t < NB) hist[t] = 0;
    for (int i = t; i < N_GRAPHS; i += 256) ghist[i] = 0;
    __syncthreads();
    // batch counting: block covers nodes [blk*128, blk*128+128)
    if (t < 128) {
        int n = blockIdx.x * 128 + t;
        if (n < N_NODES) atomicAdd(&ghist[loadi(batch, n, I64)], 1);
    }
    // edge pass 1: decode once, stage in LDS, bucket counts
    int e0 = blockIdx.x * EPB;
#pragma unroll 4
    for (int it = 0; it < EPB / 256; ++it) {
        int idx = it * 256 + t;
        int e = e0 + idx;
        unsigned int pv = 0u;
        unsigned char bk = 0xFFu;
        if (e < N_EDGES) {
            int sN = loadi(ei, e, I64);
            int d = loadi(ei, (size_t)N_EDGES + e, I64);
            bk = (unsigned char)(d >> SH);
            pv = ((unsigned int)sN << SH) | (unsigned int)(d & 511);
            atomicAdd(&hist[d >> SH], 1);
        }
        elds[idx] = pv;
        ebkt[idx] = bk;
    }
    __syncthreads();
    if (t < NB) {
        base[t] = hist[t] ? atomicAdd(&bcnt[t], hist[t]) : 0;
        hist[t] = 0;   // reuse as pass-2 rank counter
    }
    for (int i = t; i < N_GRAPHS; i += 256)
        if (ghist[i]) atomicAdd(&gcnt[i], ghist[i]);
    __syncthreads();
    // edge pass 2: rank + write from LDS
#pragma unroll 4
    for (int it = 0; it < EPB / 256; ++it) {
        int idx = it * 256 + t;
        unsigned char bk = ebkt[idx];
        if (bk != 0xFFu) {
            unsigned int pv = elds[idx];
            int r = atomicAdd(&hist[bk], 1);
            int pos = base[bk] + r;
            if (pos < BCAP)
                packed[(size_t)bk * BCAP + pos] = pv;
        }
    }
}

// ---------------- fused CSR build + graph scan --------------------------------
__global__ __launch_bounds__(512) void k_csr(const unsigned int* __restrict__ packed,
                                             const int* __restrict__ bcnt,
                                             float* __restrict__ dis,
                                             int2* __restrict__ rp2,
                                             int* __restrict__ csr,
                                             const int* __restrict__ gcnt,
                                             int* __restrict__ gptr) {
    __shared__ int hist[512];
    __shared__ int offs[512];
    __shared__ int elds[BCAP];    // 38 KB
    int b = blockIdx.x;
    int t = threadIdx.x;
    if (b == NBU) {
        // graph scan: gcnt (1024) -> gptr
        int a = gcnt[2 * t], bq = gcnt[2 * t + 1];
        int ps = a + bq;
        hist[t] = ps;
        __syncthreads();
        for (int off = 1; off < 512; off <<= 1) {
            int x = (t >= off) ? hist[t - off] : 0;
            __syncthreads();
            hist[t] += x;
            __syncthreads();
        }
        int excl = hist[t] - ps;
        gptr[2 * t] = excl;
        gptr[2 * t + 1] = excl + a;
        if (t == 511) gptr[1024] = hist[511];
        return;
    }
    int n = bcnt[b]; if (n > BCAP) n = BCAP;
    hist[t] = 0;
    __syncthreads();
    const unsigned int* pb = packed + (size_t)b * BCAP;
    for (int i = t; i < n; i += 512)
        atomicAdd(&hist[pb[i] & 511u], 1);
    __syncthreads();
    int c = hist[t];
    offs[t] = c;
    __syncthreads();
    for (int off = 1; off < 512; off <<= 1) {
        int x = (t >= off) ? offs[t - off] : 0;
        __syncthreads();
        offs[t] += x;
        __syncthreads();
    }
    int excl = offs[t] - c;
    int node = (b << SH) + t;
    int base = b * BCAP;
    if (node < N_NODES) {
        dis[node] = rsqrtf((float)c + 1.0f);
        rp2[node] = make_int2(base + excl, base + excl + c);
    }
    __syncthreads();
    offs[t] = excl;               // running scatter counters
    __syncthreads();
    for (int i = t; i < n; i += 512) {
        unsigned int p = pb[i];
        int pos = atomicAdd(&offs[p & 511u], 1);
        if (pos < BCAP) elds[pos] = (int)(p >> SH);
    }
    __syncthreads();
    for (int i = t; i < n; i += 512)
        csr[base + i] = elds[i];
}

// ---------------- MFMA GEMM (layer 1): x[N,128] @ W1 -> slice-major bf16 ------
template <int K>
__global__ __launch_bounds__(256) void k_gemm(const void* __restrict__ x,
                                              const void* __restrict__ W,
                                              const float* __restrict__ dis,
                                              unsigned short* __restrict__ out,  // bf16 bits
                                              const int* __restrict__ flags,
                                              int x_is_f32) {
    int Wf32 = flags[0];
    int xF32 = (x_is_f32 < 0) ? Wf32 : x_is_f32;
    __shared__ unsigned short Wt[64][K + 8];
    __shared__ unsigned short xs[32][K + 8];
    int t = threadIdx.x;
    int wave = t >> 6, lane = t & 63;
    int quad = lane >> 4, l16 = lane & 15;

    for (int id = t; id < 64 * K; id += 256) {
        int k = id >> 6, n = id & 63;
        Wt[n][k] = f2bf(loadf(W, id, Wf32));
    }
    __syncthreads();

    bf16x8 bfrag[K / 32];
#pragma unroll
    for (int c = 0; c < K / 32; ++c)
        bfrag[c] = *reinterpret_cast<bf16x8*>(&Wt[wave * 16 + l16][c * 32 + quad * 8]);

    const int ngroups = (N_NODES + 31) / 32;
    for (int g = blockIdx.x; g < ngroups; g += gridDim.x) {
        __syncthreads();
        int row0 = g * 32;
        for (int cid = t; cid < 4 * K; cid += 256) {
            int rr = cid / (K / 8), c8 = cid % (K / 8);
            int r = row0 + rr;
            u32x4 val = {0u, 0u, 0u, 0u};
            if (r < N_NODES) {
                size_t base = (size_t)r * K + c8 * 8;
                if (xF32) {
                    const u32x4* xp = (const u32x4*)x;
                    u32x4 q0 = xp[base / 4];
                    u32x4 q1 = xp[base / 4 + 1];
                    val.x = f2bf(__uint_as_float(q0.x)) | ((unsigned int)f2bf(__uint_as_float(q0.y)) << 16);
                    val.y = f2bf(__uint_as_float(q0.z)) | ((unsigned int)f2bf(__uint_as_float(q0.w)) << 16);
                    val.z = f2bf(__uint_as_float(q1.x)) | ((unsigned int)f2bf(__uint_as_float(q1.y)) << 16);
                    val.w = f2bf(__uint_as_float(q1.z)) | ((unsigned int)f2bf(__uint_as_float(q1.w)) << 16);
                } else {
                    val = ((const u32x4*)x)[base / 8];
                }
            }
            *reinterpret_cast<u32x4*>(&xs[rr][c8 * 8]) = val;
        }
        __syncthreads();

        f32x4 acc0 = {0.f, 0.f, 0.f, 0.f};
        f32x4 acc1 = {0.f, 0.f, 0.f, 0.f};
#pragma unroll
        for (int c = 0; c < K / 32; ++c) {
            bf16x8 a0 = *reinterpret_cast<bf16x8*>(&xs[l16][c * 32 + quad * 8]);
            bf16x8 a1 = *reinterpret_cast<bf16x8*>(&xs[16 + l16][c * 32 + quad * 8]);
            acc0 = __builtin_amdgcn_mfma_f32_16x16x32_bf16(a0, bfrag[c], acc0, 0, 0, 0);
            acc1 = __builtin_amdgcn_mfma_f32_16x16x32_bf16(a1, bfrag[c], acc1, 0, 0, 0);
        }
        int col = wave * 16 + l16;
        unsigned short* ow = out + (size_t)(col >> 5) * (N_NODES * 32);
        int f = col & 31;
#pragma unroll
        for (int reg = 0; reg < 4; ++reg) {
            int r0 = row0 + quad * 4 + reg;
            if (r0 < N_NODES) ow[(size_t)r0 * 32 + f] = f2bf(acc0[reg] * dis[r0]);
            int r1 = row0 + 16 + quad * 4 + reg;
            if (r1 < N_NODES) ow[(size_t)r1 * 32 + f] = f2bf(acc1[reg] * dis[r1]);
        }
    }
}

// ---------------- layer-1 gather (R11: 2-ahead row pipeline) ------------------
// Issue row i+1 (index already in hand) BEFORE consuming row i; fetch index
// i+2 in the same slot -> 2 rows in flight per lane, exposed latency ~halved.
// lane = nodesub(4) x eslot(4) x quarter(4); out node-major hs1 = relu(h1)*dis.
__global__ __launch_bounds__(256) void k_gather_sm(const int2* __restrict__ rp2,
                                                   const int* __restrict__ csr,
                                                   const float* __restrict__ dis,
                                                   const unsigned short* __restrict__ xws,
                                                   const void* __restrict__ bias,
                                                   unsigned short* __restrict__ out,
                                                   const int* __restrict__ flags) {
    int F32 = flags[0];
    int blk = blockIdx.x;
    int xcd = blk & 7;
    int s = xcd >> 2;                              // slice 0..1
    int grp = ((blk >> 3) << 2) | (xcd & 3);       // 64-node group
    int wave = threadIdx.x >> 6, lane = threadIdx.x & 63;
    int nodesub = lane >> 4;                       // 0..3
    int eslot = (lane >> 2) & 3;                   // 0..3
    int q = lane & 3;                              // 0..3 (16-B quarter of 64-B row)
    const u32x4* xs4 = (const u32x4*)(xws + (size_t)s * N_NODES * 32);  // row = 4 u32x4
    u32x4* op = (u32x4*)out;                       // node-major [N][64]: 8 u32x4/row
    float bb0 = loadf(bias, s * 32 + q * 8 + 0, F32);
    float bb1 = loadf(bias, s * 32 + q * 8 + 1, F32);
    float bb2 = loadf(bias, s * 32 + q * 8 + 2, F32);
    float bb3 = loadf(bias, s * 32 + q * 8 + 3, F32);
    float bb4 = loadf(bias, s * 32 + q * 8 + 4, F32);
    float bb5 = loadf(bias, s * 32 + q * 8 + 5, F32);
    float bb6 = loadf(bias, s * 32 + q * 8 + 6, F32);
    float bb7 = loadf(bias, s * 32 + q * 8 + 7, F32);
    int wbase = grp * 64 + wave * 16;

    for (int ni = 0; ni < 4; ++ni) {
        int node = wbase + ni * 4 + nodesub;
        int valid = node < N_NODES;
        int2 se = valid ? rp2[node] : make_int2(0, 0);
        float a0 = 0.f, a1 = 0.f, a2 = 0.f, a3 = 0.f;
        float a4 = 0.f, a5 = 0.f, a6 = 0.f, a7 = 0.f;
        int j = se.x + eslot;
        if (j < se.y) {
            int src = csr[j];
            u32x4 vc = xs4[(size_t)src * 4 + q];
            int jn = j + 4;
            int sn = (jn < se.y) ? csr[jn] : 0;
            while (jn < se.y) {
                u32x4 vn = xs4[(size_t)sn * 4 + q];   // row i+1 in flight
                int jn2 = jn + 4;
                int sn2 = (jn2 < se.y) ? csr[jn2] : 0; // index i+2 in flight
                a0 += bf2f(vc.x & 0xFFFFu); a1 += bf2f(vc.x >> 16);
                a2 += bf2f(vc.y & 0xFFFFu); a3 += bf2f(vc.y >> 16);
                a4 += bf2f(vc.z & 0xFFFFu); a5 += bf2f(vc.z >> 16);
                a6 += bf2f(vc.w & 0xFFFFu); a7 += bf2f(vc.w >> 16);
                vc = vn; sn = sn2; jn = jn2;
            }
            a0 += bf2f(vc.x & 0xFFFFu); a1 += bf2f(vc.x >> 16);
            a2 += bf2f(vc.y & 0xFFFFu); a3 += bf2f(vc.y >> 16);
            a4 += bf2f(vc.z & 0xFFFFu); a5 += bf2f(vc.z >> 16);
            a6 += bf2f(vc.w & 0xFFFFu); a7 += bf2f(vc.w >> 16);
        }
#pragma unroll
        for (int off = 4; off <= 8; off <<= 1) {
            a0 += __shfl_down(a0, off, 64); a1 += __shfl_down(a1, off, 64);
            a2 += __shfl_down(a2, off, 64); a3 += __shfl_down(a3, off, 64);
            a4 += __shfl_down(a4, off, 64); a5 += __shfl_down(a5, off, 64);
            a6 += __shfl_down(a6, off, 64); a7 += __shfl_down(a7, off, 64);
        }
        if (((lane & 12) == 0) && valid) {   // eslot == 0
            u32x4 sv = xs4[(size_t)node * 4 + q];   // self row (cache-hot)
            float dn = dis[node];
            float v0 = fmaf(a0 + bf2f(sv.x & 0xFFFFu), dn, bb0);
            float v1 = fmaf(a1 + bf2f(sv.x >> 16),     dn, bb1);
            float v2 = fmaf(a2 + bf2f(sv.y & 0xFFFFu), dn, bb2);
            float v3 = fmaf(a3 + bf2f(sv.y >> 16),     dn, bb3);
            float v4 = fmaf(a4 + bf2f(sv.z & 0xFFFFu), dn, bb4);
            float v5 = fmaf(a5 + bf2f(sv.z >> 16),     dn, bb5);
            float v6 = fmaf(a6 + bf2f(sv.w & 0xFFFFu), dn, bb6);
            float v7 = fmaf(a7 + bf2f(sv.w >> 16),     dn, bb7);
            // hs1 = relu(h1) * dis
            v0 = fmaxf(v0, 0.f) * dn; v1 = fmaxf(v1, 0.f) * dn;
            v2 = fmaxf(v2, 0.f) * dn; v3 = fmaxf(v3, 0.f) * dn;
            v4 = fmaxf(v4, 0.f) * dn; v5 = fmaxf(v5, 0.f) * dn;
            v6 = fmaxf(v6, 0.f) * dn; v7 = fmaxf(v7, 0.f) * dn;
            u32x4 o;
            o.x = (unsigned int)f2bf(v0) | ((unsigned int)f2bf(v1) << 16);
            o.y = (unsigned int)f2bf(v2) | ((unsigned int)f2bf(v3) << 16);
            o.z = (unsigned int)f2bf(v4) | ((unsigned int)f2bf(v5) << 16);
            o.w = (unsigned int)f2bf(v6) | ((unsigned int)f2bf(v7) << 16);
            op[(size_t)node * 8 + s * 4 + q] = o;
        }
    }
}

// ---------------- fused layer 2: agg-first gather + MFMA GEMM -----------------
// g[dst] = dis[dst]*(Σ hs[src] + hs[dst]) staged in LDS, then @W2 (+b2, relu,
// *dis -> hs2). R11: 2-ahead row pipeline in the gather loop.
__global__ __launch_bounds__(256) void k_fgl(const int2* __restrict__ rp2,
                                             const int* __restrict__ csr,
                                             const float* __restrict__ dis,
                                             const unsigned short* __restrict__ hs_in,
                                             const void* __restrict__ W,
                                             const void* __restrict__ bias,
                                             unsigned short* __restrict__ out,
                                             int relu_scale,
                                             const int* __restrict__ flags) {
    int F32 = flags[0];
    __shared__ unsigned short Wt[64][72];
    __shared__ unsigned short xs[64][72];
    int t = threadIdx.x;
    int w = t >> 6, lane = t & 63;
    for (int id = t; id < 64 * 64; id += 256) {
        int k = id >> 6, n = id & 63;
        Wt[n][k] = f2bf(loadf(W, id, F32));
    }
    // ---- gather phase ----
    int node2 = lane >> 5;          // 0..1
    int oct = lane & 7;             // 0..7 (16-B chunk of 128-B row)
    const u32x4* xr = (const u32x4*)hs_in;   // row = 8 u32x4
    int wbase = blockIdx.x * 64 + w * 16;
#pragma unroll
    for (int p = 0; p < 8; ++p) {
        int node = wbase + p * 2 + node2;
        int valid = node < N_NODES;
        int2 se = valid ? rp2[node] : make_int2(0, 0);
        float a0 = 0.f, a1 = 0.f, a2 = 0.f, a3 = 0.f;
        float a4 = 0.f, a5 = 0.f, a6 = 0.f, a7 = 0.f;
        int j = se.x + ((lane >> 3) & 3);    // eslot
        if (j < se.y) {
            int src = csr[j];
            u32x4 vc = xr[(size_t)src * 8 + oct];
            int jn = j + 4;
            int sn = (jn < se.y) ? csr[jn] : 0;
            while (jn < se.y) {
                u32x4 vn = xr[(size_t)sn * 8 + oct];
                int jn2 = jn + 4;
                int sn2 = (jn2 < se.y) ? csr[jn2] : 0;
                a0 += bf2f(vc.x & 0xFFFFu); a1 += bf2f(vc.x >> 16);
                a2 += bf2f(vc.y & 0xFFFFu); a3 += bf2f(vc.y >> 16);
                a4 += bf2f(vc.z & 0xFFFFu); a5 += bf2f(vc.z >> 16);
                a6 += bf2f(vc.w & 0xFFFFu); a7 += bf2f(vc.w >> 16);
                vc = vn; sn = sn2; jn = jn2;
            }
            a0 += bf2f(vc.x & 0xFFFFu); a1 += bf2f(vc.x >> 16);
            a2 += bf2f(vc.y & 0xFFFFu); a3 += bf2f(vc.y >> 16);
            a4 += bf2f(vc.z & 0xFFFFu); a5 += bf2f(vc.z >> 16);
            a6 += bf2f(vc.w & 0xFFFFu); a7 += bf2f(vc.w >> 16);
        }
        // reduce over eslot (lane bits 3-4: offsets 8, 16)
#pragma unroll
        for (int off = 8; off <= 16; off <<= 1) {
            a0 += __shfl_down(a0, off, 64); a1 += __shfl_down(a1, off, 64);
            a2 += __shfl_down(a2, off, 64); a3 += __shfl_down(a3, off, 64);
            a4 += __shfl_down(a4, off, 64); a5 += __shfl_down(a5, off, 64);
            a6 += __shfl_down(a6, off, 64); a7 += __shfl_down(a7, off, 64);
        }
        if ((lane & 24) == 0) {   // eslot == 0: lanes 0-7 and 32-39
            u32x4 sv = {0u, 0u, 0u, 0u};
            float dn = 0.f;
            if (valid) { sv = xr[(size_t)node * 8 + oct]; dn = dis[node]; }
            float v0 = (a0 + bf2f(sv.x & 0xFFFFu)) * dn;
            float v1 = (a1 + bf2f(sv.x >> 16))     * dn;
            float v2 = (a2 + bf2f(sv.y & 0xFFFFu)) * dn;
            float v3 = (a3 + bf2f(sv.y >> 16))     * dn;
            float v4 = (a4 + bf2f(sv.z & 0xFFFFu)) * dn;
            float v5 = (a5 + bf2f(sv.z >> 16))     * dn;
            float v6 = (a6 + bf2f(sv.w & 0xFFFFu)) * dn;
            float v7 = (a7 + bf2f(sv.w >> 16))     * dn;
            u32x4 o;
            o.x = (unsigned int)f2bf(v0) | ((unsigned int)f2bf(v1) << 16);
            o.y = (unsigned int)f2bf(v2) | ((unsigned int)f2bf(v3) << 16);
            o.z = (unsigned int)f2bf(v4) | ((unsigned int)f2bf(v5) << 16);
            o.w = (unsigned int)f2bf(v6) | ((unsigned int)f2bf(v7) << 16);
            *reinterpret_cast<u32x4*>(&xs[w * 16 + p * 2 + node2][oct * 8]) = o;
        }
    }
    __syncthreads();
    // ---- MFMA phase: 64 rows x 64 cols, K=64 ----
    int quad = lane >> 4, l16 = lane & 15;
    bf16x8 bfrag[2];
#pragma unroll
    for (int c = 0; c < 2; ++c)
        bfrag[c] = *reinterpret_cast<bf16x8*>(&Wt[w * 16 + l16][c * 32 + quad * 8]);
    f32x4 acc[4];
#pragma unroll
    for (int rg = 0; rg < 4; ++rg) acc[rg] = (f32x4){0.f, 0.f, 0.f, 0.f};
#pragma unroll
    for (int c = 0; c < 2; ++c) {
#pragma unroll
        for (int rg = 0; rg < 4; ++rg) {
            bf16x8 a = *reinterpret_cast<bf16x8*>(&xs[rg * 16 + l16][c * 32 + quad * 8]);
            acc[rg] = __builtin_amdgcn_mfma_f32_16x16x32_bf16(a, bfrag[c], acc[rg], 0, 0, 0);
        }
    }
    int col = w * 16 + l16;
    float bcol = loadf(bias, col, F32);
    int rbase = blockIdx.x * 64;
#pragma unroll
    for (int rg = 0; rg < 4; ++rg) {
#pragma unroll
        for (int reg = 0; reg < 4; ++reg) {
            int row = rbase + rg * 16 + quad * 4 + reg;
            if (row < N_NODES) {
                float v = acc[rg][reg] + bcol;
                if (relu_scale) v = fmaxf(v, 0.f) * dis[row];
                out[(size_t)row * 64 + col] = f2bf(v);
            }
        }
    }
}

// ---------------- fused layer 3 + pool + head ---------------------------------
// Pool is linear and layer 3 has no relu:
//   out[g] = mean_g(agg3) . (W3@Wl) + b3.Wl + bl,  agg3[i] = dis_i(Σ hs2_j + hs2_i)
// Per-lane pooled partials: dis_i multiplies linearly -> NO per-node shuffles.
// Block = 1 graph; wave strides nodes; lane = eslot(8) x oct(8); 2-ahead pipeline.
__global__ __launch_bounds__(256) void k_pool3(const int* __restrict__ gptr,
                                               const int2* __restrict__ rp2,
                                               const int* __restrict__ csr,
                                               const float* __restrict__ dis,
                                               const unsigned short* __restrict__ hs,
                                               const void* __restrict__ W3,
                                               const void* __restrict__ b3,
                                               const void* __restrict__ Wl,
                                               const void* __restrict__ bl,
                                               void* __restrict__ out,
                                               const int* __restrict__ flags) {
    int F32 = flags[0];
    __shared__ float w3l[64];
    __shared__ float part[4];
    __shared__ float cterm;
    int t = threadIdx.x;
    if (t < 64) {
        float acc = 0.f;
        for (int k = 0; k < 64; ++k)
            acc += loadf(W3, t * 64 + k, F32) * loadf(Wl, k, F32);
        w3l[t] = acc;
    }
    if (t == 64) {
        float acc = 0.f;
        for (int k = 0; k < 64; ++k)
            acc += loadf(b3, k, F32) * loadf(Wl, k, F32);
        cterm = acc;
    }
    __syncthreads();
    int g = blockIdx.x;
    int w = t >> 6, lane = t & 63;
    int eslot = lane >> 3, oct = lane & 7;
    int s0 = gptr[g], e0 = gptr[g + 1];
    const u32x4* xr = (const u32x4*)hs;   // row = 8 u32x4
    float P0 = 0.f, P1 = 0.f, P2 = 0.f, P3 = 0.f;
    float P4 = 0.f, P5 = 0.f, P6 = 0.f, P7 = 0.f;
    for (int node = s0 + w; node < e0; node += 4) {
        int2 se = rp2[node];
        float t0 = 0.f, t1 = 0.f, t2 = 0.f, t3 = 0.f;
        float t4 = 0.f, t5 = 0.f, t6 = 0.f, t7 = 0.f;
        int j = se.x + eslot;
        if (j < se.y) {
            int src = csr[j];
            u32x4 vc = xr[(size_t)src * 8 + oct];
            int jn = j + 8;
            int sn = (jn < se.y) ? csr[jn] : 0;
            while (jn < se.y) {
                u32x4 vn = xr[(size_t)sn * 8 + oct];
                int jn2 = jn + 8;
                int sn2 = (jn2 < se.y) ? csr[jn2] : 0;
                t0 += bf2f(vc.x & 0xFFFFu); t1 += bf2f(vc.x >> 16);
                t2 += bf2f(vc.y & 0xFFFFu); t3 += bf2f(vc.y >> 16);
                t4 += bf2f(vc.z & 0xFFFFu); t5 += bf2f(vc.z >> 16);
                t6 += bf2f(vc.w & 0xFFFFu); t7 += bf2f(vc.w >> 16);
                vc = vn; sn = sn2; jn = jn2;
            }
            t0 += bf2f(vc.x & 0xFFFFu); t1 += bf2f(vc.x >> 16);
            t2 += bf2f(vc.y & 0xFFFFu); t3 += bf2f(vc.y >> 16);
            t4 += bf2f(vc.z & 0xFFFFu); t5 += bf2f(vc.z >> 16);
            t6 += bf2f(vc.w & 0xFFFFu); t7 += bf2f(vc.w >> 16);
        }
        if (eslot == 0) {   // self-loop contribution
            u32x4 sv = xr[(size_t)node * 8 + oct];
            t0 += bf2f(sv.x & 0xFFFFu); t1 += bf2f(sv.x >> 16);
            t2 += bf2f(sv.y & 0xFFFFu); t3 += bf2f(sv.y >> 16);
            t4 += bf2f(sv.z & 0xFFFFu); t5 += bf2f(sv.z >> 16);
            t6 += bf2f(sv.w & 0xFFFFu); t7 += bf2f(sv.w >> 16);
        }
        float dn = dis[node];
        P0 = fmaf(t0, dn, P0); P1 = fmaf(t1, dn, P1);
        P2 = fmaf(t2, dn, P2); P3 = fmaf(t3, dn, P3);
        P4 = fmaf(t4, dn, P4); P5 = fmaf(t5, dn, P5);
        P6 = fmaf(t6, dn, P6); P7 = fmaf(t7, dn, P7);
    }
    // reduce over eslot (lane bits 3-5: offsets 8,16,32)
#pragma unroll
    for (int off = 8; off <= 32; off <<= 1) {
        P0 += __shfl_down(P0, off, 64); P1 += __shfl_down(P1, off, 64);
        P2 += __shfl_down(P2, off, 64); P3 += __shfl_down(P3, off, 64);
        P4 += __shfl_down(P4, off, 64); P5 += __shfl_down(P5, off, 64);
        P6 += __shfl_down(P6, off, 64); P7 += __shfl_down(P7, off, 64);
    }
    float v = 0.f;
    if (eslot == 0) {   // lanes 0-7 hold feats oct*8..oct*8+7
        int f = oct * 8;
        v = P0 * w3l[f] + P1 * w3l[f + 1] + P2 * w3l[f + 2] + P3 * w3l[f + 3]
          + P4 * w3l[f + 4] + P5 * w3l[f + 5] + P6 * w3l[f + 6] + P7 * w3l[f + 7];
    }
    v += __shfl_down(v, 4, 64);
    v += __shfl_down(v, 2, 64);
    v += __shfl_down(v, 1, 64);
    if (lane == 0) part[w] = v;
    __syncthreads();
    if (t == 0) {
        float cnt = fmaxf((float)(e0 - s0), 1.0f);
        float r = (part[0] + part[1] + part[2] + part[3]) / cnt
                + ((e0 > s0) ? cterm : 0.f) + loadf(bl, 0, F32);
        if (F32) ((float*)out)[g] = r;
        else     ((__hip_bfloat16*)out)[g] = __float2bfloat16(r);
    }
}

extern "C" void kernel_launch(void* const* d_in, const int* in_sizes, int n_in,
                              void* d_out, int out_size, void* d_ws, size_t ws_size,
                              hipStream_t stream) {
    const void* x     = d_in[0];
    const void* ei    = d_in[1];
    const void* batch = d_in[2];
    const void* W1 = d_in[3];
    const void* b1 = d_in[4];
    const void* W2 = d_in[5];
    const void* b2 = d_in[6];
    const void* W3 = d_in[7];
    const void* b3 = d_in[8];
    const void* Wl = d_in[9];
    const void* bl = d_in[10];

    // workspace layout (~42 MB)
    float* dis   = (float*)d_ws;             // 100352
    int2*  rp2   = (int2*)(dis + 100352);    // 100352 int2 (start,end)
    int*   csr   = (int*)(rp2 + 100352);     // NB*BCAP (per-bucket dense, 7.8 MB)
    int*   gcnt  = csr + NB * BCAP;          // 1024
    int*   gptr  = gcnt + 1024;              // 1056 (needs 1025)
    int*   bcnt  = gptr + 1056;              // 256
    int*   flags = bcnt + 256;               // 16
    unsigned int* packed = (unsigned int*)(flags + 16);    // NB*BCAP (7.8 MB)
    unsigned short* bufA = (unsigned short*)(packed + (size_t)NB * BCAP);  // 12.8 MB
    unsigned short* bufB = bufA + (size_t)N_NODES * 64;                    // 12.8 MB

    const int TB = 256;
    dim3 blk(TB);
    int gGA = 391 * 8;                       // layer-1 gather grid
    int gFG = (N_NODES + 63) / 64;           // 1563 fused-layer blocks

    // init: detect + zero small counters
    k_init<<<1, blk, 0, stream>>>((const unsigned int*)x, (const unsigned int*)ei,
                                  flags, gcnt, bcnt);
    // phase A partition
    k_part<<<(N_EDGES + EPB - 1) / EPB, blk, 0, stream>>>(ei, batch, bcnt, gcnt, packed, flags);
    // fused CSR build + graph scan
    k_csr<<<NBU + 1, 512, 0, stream>>>(packed, bcnt, dis, rp2, csr, gcnt, gptr);

    // ---- layer 1: transform-first (128 -> 64), then gather -> hs1 node-major --
    k_gemm<F_IN><<<1024, blk, 0, stream>>>(x, W1, dis, bufA, flags, -1);
    k_gather_sm<<<gGA, blk, 0, stream>>>(rp2, csr, dis, bufA, b1, bufB, flags);
    // ---- layer 2: fused agg-first gather + GEMM -> hs2 ----
    k_fgl<<<gFG, blk, 0, stream>>>(rp2, csr, dis, bufB, W2, b2, bufA, 1, flags);
    // ---- layer 3 + pool + head: fused (pool linear, no relu on layer 3) ----
    k_pool3<<<N_GRAPHS, blk, 0, stream>>>(gptr, rp2, csr, dis, bufA,
                                          W3, b3, Wl, bl, d_out, flags);
}

// Round 12
// 313.163 us; speedup vs baseline: 1.0929x; 1.0929x over previous
//
#include <hip/hip_runtime.h>
#include <hip/hip_bf16.h>

#define N_NODES 100000
#define N_EDGES 1600000
#define F_IN 128
#define HID 64
#define N_GRAPHS 1024

// fine dst-partition: bucket = dst>>9 (512 nodes/bucket)
#define SH 9
#define NBU 196        // buckets used: ceil(100000/512)
#define NB 200         // allocated
#define BCAP 9728      // mean 8192 + 17 sigma
#define EPB 2048       // edges per k_part block (782 blocks, ~3/CU)
#define NSLICE 2       // gemm1 output: 2 slices x 32 feats (64-B rows)

typedef __attribute__((ext_vector_type(8))) short bf16x8;
typedef __attribute__((ext_vector_type(4))) float f32x4;
typedef __attribute__((ext_vector_type(4))) unsigned int u32x4;

// ---------------- bf16 bit helpers --------------------------------------------
__device__ __forceinline__ unsigned short f2bf(float f) {
    __hip_bfloat16 h = __float2bfloat16(f);   // RNE
    return *reinterpret_cast<unsigned short*>(&h);
}
__device__ __forceinline__ float bf2f(unsigned int u) {
    return __uint_as_float(u << 16);
}

// ---------------- dual-path load helpers (wire dtype resolved at runtime) -----
__device__ __forceinline__ float loadf(const void* p, size_t i, int f32) {
    if (f32) return ((const float*)p)[i];
    return __bfloat162float(((const __hip_bfloat16*)p)[i]);
}
__device__ __forceinline__ int loadi(const void* p, size_t i, int i64) {
    if (i64) return (int)((const long long*)p)[i];
    return ((const int*)p)[i];
}

// ---------------- init: wire detect + w3l/cterm precompute + zero counters ----
// R12: w3l = W3@Wl (64 f32, w3l[64]=b3.Wl) computed here; gacc zeroed here.
__global__ void k_init(const unsigned int* __restrict__ xw_,
                       const unsigned int* __restrict__ ei_,
                       int* __restrict__ flags,
                       int* __restrict__ gcnt, int* __restrict__ bcnt,
                       const void* __restrict__ W3, const void* __restrict__ b3,
                       const void* __restrict__ Wl,
                       float* __restrict__ w3l, float* __restrict__ gacc) {
    __shared__ int cnt_f, cnt_i, sF32;
    int t = threadIdx.x;
    if (t == 0) { cnt_f = 0; cnt_i = 0; }
    __syncthreads();
    unsigned int w = xw_[t];
    unsigned int e = (w >> 7) & 0xFFu;
    if (e >= 100u && e <= 140u) atomicAdd(&cnt_f, 1);
    unsigned int iw = ei_[2 * t + 1];
    if (iw == 0u) atomicAdd(&cnt_i, 1);
    for (int i = t; i < N_GRAPHS; i += 256) { gcnt[i] = 0; gacc[i] = 0.f; }
    for (int i = t; i < NB; i += 256) bcnt[i] = 0;
    __syncthreads();
    if (t == 0) {
        int f = (cnt_f < 180) ? 1 : 0;
        flags[0] = f;                       // 1 => fp32 wire
        flags[1] = (cnt_i >= 128) ? 1 : 0;  // 1 => int64 wire
        sF32 = f;
    }
    __syncthreads();
    int F32 = sF32;
    if (t < 64) {
        float acc = 0.f;
        for (int k = 0; k < 64; ++k)
            acc += loadf(W3, t * 64 + k, F32) * loadf(Wl, k, F32);
        w3l[t] = acc;
    }
    if (t == 64) {
        float acc = 0.f;
        for (int k = 0; k < 64; ++k)
            acc += loadf(b3, k, F32) * loadf(Wl, k, F32);
        w3l[64] = acc;   // cterm
    }
}

// ---------------- phase A: partition by dst>>9, two-pass blocks ---------------
__global__ __launch_bounds__(256) void k_part(const void* __restrict__ ei,
                                              const void* __restrict__ batch,
                                              int* __restrict__ bcnt,
                                              int* __restrict__ gcnt,
                                              unsigned int* __restrict__ packed,
                                              const int* __restrict__ flags) {
    int I64 = flags[1];
    __shared__ int hist[NB];
    __shared__ int base[NB];
    __shared__ int ghist[N_GRAPHS];        // 4 KB
    __shared__ unsigned int elds[EPB];     // 8 KB: packed words
    __shared__ unsigned char ebkt[EPB];    // 2 KB: bucket ids (0xFF = invalid)
    int t = threadIdx.x;
    if (t < NB) hist[t] = 0;
    for (int i = t; i < N_GRAPHS; i += 256) ghist[i] = 0;
    __syncthreads();
    // batch counting: block covers nodes [blk*128, blk*128+128)
    if (t < 128) {
        int n = blockIdx.x * 128 + t;
        if (n < N_NODES) atomicAdd(&ghist[loadi(batch, n, I64)], 1);
    }
    // edge pass 1: decode once, stage in LDS, bucket counts
    int e0 = blockIdx.x * EPB;
#pragma unroll 4
    for (int it = 0; it < EPB / 256; ++it) {
        int idx = it * 256 + t;
        int e = e0 + idx;
        unsigned int pv = 0u;
        unsigned char bk = 0xFFu;
        if (e < N_EDGES) {
            int sN = loadi(ei, e, I64);
            int d = loadi(ei, (size_t)N_EDGES + e, I64);
            bk = (unsigned char)(d >> SH);
            pv = ((unsigned int)sN << SH) | (unsigned int)(d & 511);
            atomicAdd(&hist[d >> SH], 1);
        }
        elds[idx] = pv;
        ebkt[idx] = bk;
    }
    __syncthreads();
    if (t < NB) {
        base[t] = hist[t] ? atomicAdd(&bcnt[t], hist[t]) : 0;
        hist[t] = 0;   // reuse as pass-2 rank counter
    }
    for (int i = t; i < N_GRAPHS; i += 256)
        if (ghist[i]) atomicAdd(&gcnt[i], ghist[i]);
    __syncthreads();
    // edge pass 2: rank + write from LDS
#pragma unroll 4
    for (int it = 0; it < EPB / 256; ++it) {
        int idx = it * 256 + t;
        unsigned char bk = ebkt[idx];
        if (bk != 0xFFu) {
            unsigned int pv = elds[idx];
            int r = atomicAdd(&hist[bk], 1);
            int pos = base[bk] + r;
            if (pos < BCAP)
                packed[(size_t)bk * BCAP + pos] = pv;
        }
    }
}

// ---------------- fused CSR build + graph scan --------------------------------
__global__ __launch_bounds__(512) void k_csr(const unsigned int* __restrict__ packed,
                                             const int* __restrict__ bcnt,
                                             float* __restrict__ dis,
                                             int2* __restrict__ rp2,
                                             int* __restrict__ csr,
                                             const int* __restrict__ gcnt,
                                             int* __restrict__ gptr) {
    __shared__ int hist[512];
    __shared__ int offs[512];
    __shared__ int elds[BCAP];    // 38 KB
    int b = blockIdx.x;
    int t = threadIdx.x;
    if (b == NBU) {
        // graph scan: gcnt (1024) -> gptr
        int a = gcnt[2 * t], bq = gcnt[2 * t + 1];
        int ps = a + bq;
        hist[t] = ps;
        __syncthreads();
        for (int off = 1; off < 512; off <<= 1) {
            int x = (t >= off) ? hist[t - off] : 0;
            __syncthreads();
            hist[t] += x;
            __syncthreads();
        }
        int excl = hist[t] - ps;
        gptr[2 * t] = excl;
        gptr[2 * t + 1] = excl + a;
        if (t == 511) gptr[1024] = hist[511];
        return;
    }
    int n = bcnt[b]; if (n > BCAP) n = BCAP;
    hist[t] = 0;
    __syncthreads();
    const unsigned int* pb = packed + (size_t)b * BCAP;
    for (int i = t; i < n; i += 512)
        atomicAdd(&hist[pb[i] & 511u], 1);
    __syncthreads();
    int c = hist[t];
    offs[t] = c;
    __syncthreads();
    for (int off = 1; off < 512; off <<= 1) {
        int x = (t >= off) ? offs[t - off] : 0;
        __syncthreads();
        offs[t] += x;
        __syncthreads();
    }
    int excl = offs[t] - c;
    int node = (b << SH) + t;
    int base = b * BCAP;
    if (node < N_NODES) {
        dis[node] = rsqrtf((float)c + 1.0f);
        rp2[node] = make_int2(base + excl, base + excl + c);
    }
    __syncthreads();
    offs[t] = excl;               // running scatter counters
    __syncthreads();
    for (int i = t; i < n; i += 512) {
        unsigned int p = pb[i];
        int pos = atomicAdd(&offs[p & 511u], 1);
        if (pos < BCAP) elds[pos] = (int)(p >> SH);
    }
    __syncthreads();
    for (int i = t; i < n; i += 512)
        csr[base + i] = elds[i];
}

// ---------------- MFMA GEMM (layer 1): x[N,128] @ W1 -> slice-major bf16 ------
template <int K>
__global__ __launch_bounds__(256) void k_gemm(const void* __restrict__ x,
                                              const void* __restrict__ W,
                                              const float* __restrict__ dis,
                                              unsigned short* __restrict__ out,  // bf16 bits
                                              const int* __restrict__ flags,
                                              int x_is_f32) {
    int Wf32 = flags[0];
    int xF32 = (x_is_f32 < 0) ? Wf32 : x_is_f32;
    __shared__ unsigned short Wt[64][K + 8];
    __shared__ unsigned short xs[32][K + 8];
    int t = threadIdx.x;
    int wave = t >> 6, lane = t & 63;
    int quad = lane >> 4, l16 = lane & 15;

    for (int id = t; id < 64 * K; id += 256) {
        int k = id >> 6, n = id & 63;
        Wt[n][k] = f2bf(loadf(W, id, Wf32));
    }
    __syncthreads();

    bf16x8 bfrag[K / 32];
#pragma unroll
    for (int c = 0; c < K / 32; ++c)
        bfrag[c] = *reinterpret_cast<bf16x8*>(&Wt[wave * 16 + l16][c * 32 + quad * 8]);

    const int ngroups = (N_NODES + 31) / 32;
    for (int g = blockIdx.x; g < ngroups; g += gridDim.x) {
        __syncthreads();
        int row0 = g * 32;
        for (int cid = t; cid < 4 * K; cid += 256) {
            int rr = cid / (K / 8), c8 = cid % (K / 8);
            int r = row0 + rr;
            u32x4 val = {0u, 0u, 0u, 0u};
            if (r < N_NODES) {
                size_t base = (size_t)r * K + c8 * 8;
                if (xF32) {
                    const u32x4* xp = (const u32x4*)x;
                    u32x4 q0 = xp[base / 4];
                    u32x4 q1 = xp[base / 4 + 1];
                    val.x = f2bf(__uint_as_float(q0.x)) | ((unsigned int)f2bf(__uint_as_float(q0.y)) << 16);
                    val.y = f2bf(__uint_as_float(q0.z)) | ((unsigned int)f2bf(__uint_as_float(q0.w)) << 16);
                    val.z = f2bf(__uint_as_float(q1.x)) | ((unsigned int)f2bf(__uint_as_float(q1.y)) << 16);
                    val.w = f2bf(__uint_as_float(q1.z)) | ((unsigned int)f2bf(__uint_as_float(q1.w)) << 16);
                } else {
                    val = ((const u32x4*)x)[base / 8];
                }
            }
            *reinterpret_cast<u32x4*>(&xs[rr][c8 * 8]) = val;
        }
        __syncthreads();

        f32x4 acc0 = {0.f, 0.f, 0.f, 0.f};
        f32x4 acc1 = {0.f, 0.f, 0.f, 0.f};
#pragma unroll
        for (int c = 0; c < K / 32; ++c) {
            bf16x8 a0 = *reinterpret_cast<bf16x8*>(&xs[l16][c * 32 + quad * 8]);
            bf16x8 a1 = *reinterpret_cast<bf16x8*>(&xs[16 + l16][c * 32 + quad * 8]);
            acc0 = __builtin_amdgcn_mfma_f32_16x16x32_bf16(a0, bfrag[c], acc0, 0, 0, 0);
            acc1 = __builtin_amdgcn_mfma_f32_16x16x32_bf16(a1, bfrag[c], acc1, 0, 0, 0);
        }
        int col = wave * 16 + l16;
        unsigned short* ow = out + (size_t)(col >> 5) * (N_NODES * 32);
        int f = col & 31;
#pragma unroll
        for (int reg = 0; reg < 4; ++reg) {
            int r0 = row0 + quad * 4 + reg;
            if (r0 < N_NODES) ow[(size_t)r0 * 32 + f] = f2bf(acc0[reg] * dis[r0]);
            int r1 = row0 + 16 + quad * 4 + reg;
            if (r1 < N_NODES) ow[(size_t)r1 * 32 + f] = f2bf(acc1[reg] * dis[r1]);
        }
    }
}

// ---------------- layer-1 gather (2-ahead row pipeline) -----------------------
__global__ __launch_bounds__(256) void k_gather_sm(const int2* __restrict__ rp2,
                                                   const int* __restrict__ csr,
                                                   const float* __restrict__ dis,
                                                   const unsigned short* __restrict__ xws,
                                                   const void* __restrict__ bias,
                                                   unsigned short* __restrict__ out,
                                                   const int* __restrict__ flags) {
    int F32 = flags[0];
    int blk = blockIdx.x;
    int xcd = blk & 7;
    int s = xcd >> 2;                              // slice 0..1
    int grp = ((blk >> 3) << 2) | (xcd & 3);       // 64-node group
    int wave = threadIdx.x >> 6, lane = threadIdx.x & 63;
    int nodesub = lane >> 4;                       // 0..3
    int eslot = (lane >> 2) & 3;                   // 0..3
    int q = lane & 3;                              // 0..3 (16-B quarter of 64-B row)
    const u32x4* xs4 = (const u32x4*)(xws + (size_t)s * N_NODES * 32);  // row = 4 u32x4
    u32x4* op = (u32x4*)out;                       // node-major [N][64]: 8 u32x4/row
    float bb0 = loadf(bias, s * 32 + q * 8 + 0, F32);
    float bb1 = loadf(bias, s * 32 + q * 8 + 1, F32);
    float bb2 = loadf(bias, s * 32 + q * 8 + 2, F32);
    float bb3 = loadf(bias, s * 32 + q * 8 + 3, F32);
    float bb4 = loadf(bias, s * 32 + q * 8 + 4, F32);
    float bb5 = loadf(bias, s * 32 + q * 8 + 5, F32);
    float bb6 = loadf(bias, s * 32 + q * 8 + 6, F32);
    float bb7 = loadf(bias, s * 32 + q * 8 + 7, F32);
    int wbase = grp * 64 + wave * 16;

    for (int ni = 0; ni < 4; ++ni) {
        int node = wbase + ni * 4 + nodesub;
        int valid = node < N_NODES;
        int2 se = valid ? rp2[node] : make_int2(0, 0);
        float a0 = 0.f, a1 = 0.f, a2 = 0.f, a3 = 0.f;
        float a4 = 0.f, a5 = 0.f, a6 = 0.f, a7 = 0.f;
        int j = se.x + eslot;
        if (j < se.y) {
            int src = csr[j];
            u32x4 vc = xs4[(size_t)src * 4 + q];
            int jn = j + 4;
            int sn = (jn < se.y) ? csr[jn] : 0;
            while (jn < se.y) {
                u32x4 vn = xs4[(size_t)sn * 4 + q];   // row i+1 in flight
                int jn2 = jn + 4;
                int sn2 = (jn2 < se.y) ? csr[jn2] : 0; // index i+2 in flight
                a0 += bf2f(vc.x & 0xFFFFu); a1 += bf2f(vc.x >> 16);
                a2 += bf2f(vc.y & 0xFFFFu); a3 += bf2f(vc.y >> 16);
                a4 += bf2f(vc.z & 0xFFFFu); a5 += bf2f(vc.z >> 16);
                a6 += bf2f(vc.w & 0xFFFFu); a7 += bf2f(vc.w >> 16);
                vc = vn; sn = sn2; jn = jn2;
            }
            a0 += bf2f(vc.x & 0xFFFFu); a1 += bf2f(vc.x >> 16);
            a2 += bf2f(vc.y & 0xFFFFu); a3 += bf2f(vc.y >> 16);
            a4 += bf2f(vc.z & 0xFFFFu); a5 += bf2f(vc.z >> 16);
            a6 += bf2f(vc.w & 0xFFFFu); a7 += bf2f(vc.w >> 16);
        }
#pragma unroll
        for (int off = 4; off <= 8; off <<= 1) {
            a0 += __shfl_down(a0, off, 64); a1 += __shfl_down(a1, off, 64);
            a2 += __shfl_down(a2, off, 64); a3 += __shfl_down(a3, off, 64);
            a4 += __shfl_down(a4, off, 64); a5 += __shfl_down(a5, off, 64);
            a6 += __shfl_down(a6, off, 64); a7 += __shfl_down(a7, off, 64);
        }
        if (((lane & 12) == 0) && valid) {   // eslot == 0
            u32x4 sv = xs4[(size_t)node * 4 + q];   // self row (cache-hot)
            float dn = dis[node];
            float v0 = fmaf(a0 + bf2f(sv.x & 0xFFFFu), dn, bb0);
            float v1 = fmaf(a1 + bf2f(sv.x >> 16),     dn, bb1);
            float v2 = fmaf(a2 + bf2f(sv.y & 0xFFFFu), dn, bb2);
            float v3 = fmaf(a3 + bf2f(sv.y >> 16),     dn, bb3);
            float v4 = fmaf(a4 + bf2f(sv.z & 0xFFFFu), dn, bb4);
            float v5 = fmaf(a5 + bf2f(sv.z >> 16),     dn, bb5);
            float v6 = fmaf(a6 + bf2f(sv.w & 0xFFFFu), dn, bb6);
            float v7 = fmaf(a7 + bf2f(sv.w >> 16),     dn, bb7);
            // hs1 = relu(h1) * dis
            v0 = fmaxf(v0, 0.f) * dn; v1 = fmaxf(v1, 0.f) * dn;
            v2 = fmaxf(v2, 0.f) * dn; v3 = fmaxf(v3, 0.f) * dn;
            v4 = fmaxf(v4, 0.f) * dn; v5 = fmaxf(v5, 0.f) * dn;
            v6 = fmaxf(v6, 0.f) * dn; v7 = fmaxf(v7, 0.f) * dn;
            u32x4 o;
            o.x = (unsigned int)f2bf(v0) | ((unsigned int)f2bf(v1) << 16);
            o.y = (unsigned int)f2bf(v2) | ((unsigned int)f2bf(v3) << 16);
            o.z = (unsigned int)f2bf(v4) | ((unsigned int)f2bf(v5) << 16);
            o.w = (unsigned int)f2bf(v6) | ((unsigned int)f2bf(v7) << 16);
            op[(size_t)node * 8 + s * 4 + q] = o;
        }
    }
}

// ---------------- fused layer 2: agg-first gather + MFMA GEMM -----------------
__global__ __launch_bounds__(256) void k_fgl(const int2* __restrict__ rp2,
                                             const int* __restrict__ csr,
                                             const float* __restrict__ dis,
                                             const unsigned short* __restrict__ hs_in,
                                             const void* __restrict__ W,
                                             const void* __restrict__ bias,
                                             unsigned short* __restrict__ out,
                                             int relu_scale,
                                             const int* __restrict__ flags) {
    int F32 = flags[0];
    __shared__ unsigned short Wt[64][72];
    __shared__ unsigned short xs[64][72];
    int t = threadIdx.x;
    int w = t >> 6, lane = t & 63;
    for (int id = t; id < 64 * 64; id += 256) {
        int k = id >> 6, n = id & 63;
        Wt[n][k] = f2bf(loadf(W, id, F32));
    }
    // ---- gather phase ----
    int node2 = lane >> 5;          // 0..1
    int oct = lane & 7;             // 0..7 (16-B chunk of 128-B row)
    const u32x4* xr = (const u32x4*)hs_in;   // row = 8 u32x4
    int wbase = blockIdx.x * 64 + w * 16;
#pragma unroll
    for (int p = 0; p < 8; ++p) {
        int node = wbase + p * 2 + node2;
        int valid = node < N_NODES;
        int2 se = valid ? rp2[node] : make_int2(0, 0);
        float a0 = 0.f, a1 = 0.f, a2 = 0.f, a3 = 0.f;
        float a4 = 0.f, a5 = 0.f, a6 = 0.f, a7 = 0.f;
        int j = se.x + ((lane >> 3) & 3);    // eslot
        if (j < se.y) {
            int src = csr[j];
            u32x4 vc = xr[(size_t)src * 8 + oct];
            int jn = j + 4;
            int sn = (jn < se.y) ? csr[jn] : 0;
            while (jn < se.y) {
                u32x4 vn = xr[(size_t)sn * 8 + oct];
                int jn2 = jn + 4;
                int sn2 = (jn2 < se.y) ? csr[jn2] : 0;
                a0 += bf2f(vc.x & 0xFFFFu); a1 += bf2f(vc.x >> 16);
                a2 += bf2f(vc.y & 0xFFFFu); a3 += bf2f(vc.y >> 16);
                a4 += bf2f(vc.z & 0xFFFFu); a5 += bf2f(vc.z >> 16);
                a6 += bf2f(vc.w & 0xFFFFu); a7 += bf2f(vc.w >> 16);
                vc = vn; sn = sn2; jn = jn2;
            }
            a0 += bf2f(vc.x & 0xFFFFu); a1 += bf2f(vc.x >> 16);
            a2 += bf2f(vc.y & 0xFFFFu); a3 += bf2f(vc.y >> 16);
            a4 += bf2f(vc.z & 0xFFFFu); a5 += bf2f(vc.z >> 16);
            a6 += bf2f(vc.w & 0xFFFFu); a7 += bf2f(vc.w >> 16);
        }
        // reduce over eslot (lane bits 3-4: offsets 8, 16)
#pragma unroll
        for (int off = 8; off <= 16; off <<= 1) {
            a0 += __shfl_down(a0, off, 64); a1 += __shfl_down(a1, off, 64);
            a2 += __shfl_down(a2, off, 64); a3 += __shfl_down(a3, off, 64);
            a4 += __shfl_down(a4, off, 64); a5 += __shfl_down(a5, off, 64);
            a6 += __shfl_down(a6, off, 64); a7 += __shfl_down(a7, off, 64);
        }
        if ((lane & 24) == 0) {   // eslot == 0: lanes 0-7 and 32-39
            u32x4 sv = {0u, 0u, 0u, 0u};
            float dn = 0.f;
            if (valid) { sv = xr[(size_t)node * 8 + oct]; dn = dis[node]; }
            float v0 = (a0 + bf2f(sv.x & 0xFFFFu)) * dn;
            float v1 = (a1 + bf2f(sv.x >> 16))     * dn;
            float v2 = (a2 + bf2f(sv.y & 0xFFFFu)) * dn;
            float v3 = (a3 + bf2f(sv.y >> 16))     * dn;
            float v4 = (a4 + bf2f(sv.z & 0xFFFFu)) * dn;
            float v5 = (a5 + bf2f(sv.z >> 16))     * dn;
            float v6 = (a6 + bf2f(sv.w & 0xFFFFu)) * dn;
            float v7 = (a7 + bf2f(sv.w >> 16))     * dn;
            u32x4 o;
            o.x = (unsigned int)f2bf(v0) | ((unsigned int)f2bf(v1) << 16);
            o.y = (unsigned int)f2bf(v2) | ((unsigned int)f2bf(v3) << 16);
            o.z = (unsigned int)f2bf(v4) | ((unsigned int)f2bf(v5) << 16);
            o.w = (unsigned int)f2bf(v6) | ((unsigned int)f2bf(v7) << 16);
            *reinterpret_cast<u32x4*>(&xs[w * 16 + p * 2 + node2][oct * 8]) = o;
        }
    }
    __syncthreads();
    // ---- MFMA phase: 64 rows x 64 cols, K=64 ----
    int quad = lane >> 4, l16 = lane & 15;
    bf16x8 bfrag[2];
#pragma unroll
    for (int c = 0; c < 2; ++c)
        bfrag[c] = *reinterpret_cast<bf16x8*>(&Wt[w * 16 + l16][c * 32 + quad * 8]);
    f32x4 acc[4];
#pragma unroll
    for (int rg = 0; rg < 4; ++rg) acc[rg] = (f32x4){0.f, 0.f, 0.f, 0.f};
#pragma unroll
    for (int c = 0; c < 2; ++c) {
#pragma unroll
        for (int rg = 0; rg < 4; ++rg) {
            bf16x8 a = *reinterpret_cast<bf16x8*>(&xs[rg * 16 + l16][c * 32 + quad * 8]);
            acc[rg] = __builtin_amdgcn_mfma_f32_16x16x32_bf16(a, bfrag[c], acc[rg], 0, 0, 0);
        }
    }
    int col = w * 16 + l16;
    float bcol = loadf(bias, col, F32);
    int rbase = blockIdx.x * 64;
#pragma unroll
    for (int rg = 0; rg < 4; ++rg) {
#pragma unroll
        for (int reg = 0; reg < 4; ++reg) {
            int row = rbase + rg * 16 + quad * 4 + reg;
            if (row < N_NODES) {
                float v = acc[rg][reg] + bcol;
                if (relu_scale) v = fmaxf(v, 0.f) * dis[row];
                out[(size_t)row * 64 + col] = f2bf(v);
            }
        }
    }
}

// ---------------- k_z: z[i] = hs2[i] . w3l (coalesced streaming) --------------
// wave = 8 rows x 8 oct-lanes: 1 KB contiguous per wave instr; 3-level shfl.
__global__ __launch_bounds__(256) void k_z(const unsigned short* __restrict__ hs,
                                           const float* __restrict__ w3l,
                                           float* __restrict__ z) {
    __shared__ float w3s[64];
    int t = threadIdx.x;
    if (t < 64) w3s[t] = w3l[t];
    __syncthreads();
    int lane = t & 63, wave = t >> 6;
    int rowsub = lane >> 3, oct = lane & 7;
    int node = blockIdx.x * 32 + wave * 8 + rowsub;   // grid*32 == N_NODES exactly
    const u32x4* xr = (const u32x4*)hs;
    u32x4 v = xr[(size_t)node * 8 + oct];
    int f = oct * 8;
    float pd = bf2f(v.x & 0xFFFFu) * w3s[f + 0] + bf2f(v.x >> 16) * w3s[f + 1]
             + bf2f(v.y & 0xFFFFu) * w3s[f + 2] + bf2f(v.y >> 16) * w3s[f + 3]
             + bf2f(v.z & 0xFFFFu) * w3s[f + 4] + bf2f(v.z >> 16) * w3s[f + 5]
             + bf2f(v.w & 0xFFFFu) * w3s[f + 6] + bf2f(v.w >> 16) * w3s[f + 7];
    pd += __shfl_down(pd, 4, 64);
    pd += __shfl_down(pd, 2, 64);
    pd += __shfl_down(pd, 1, 64);
    if (oct == 0) z[node] = pd;
}

// ---------------- k_l3: scalar edge pass + per-node graph atomic --------------
// y_i = dis_i (Σ_{j in N(i)} z_j + z_i); gacc[batch[i]] += y_i.
// z table = 400 KB (L2-resident); csr segment per block ~20 KB (L1-hot).
__global__ __launch_bounds__(256) void k_l3(const int2* __restrict__ rp2,
                                            const int* __restrict__ csr,
                                            const float* __restrict__ dis,
                                            const float* __restrict__ z,
                                            const void* __restrict__ batch,
                                            float* __restrict__ gacc,
                                            const int* __restrict__ flags) {
    int I64 = flags[1];
    int node = blockIdx.x * 256 + threadIdx.x;
    if (node >= N_NODES) return;
    int2 se = rp2[node];
    float sum = z[node];   // self-loop
    int j = se.x;
    if (j < se.y) {
        int s = csr[j];
        for (;;) {
            int jn = j + 1;
            int sn = (jn < se.y) ? csr[jn] : 0;   // index prefetch
            sum += z[s];
            if (jn >= se.y) break;
            j = jn; s = sn;
        }
    }
    float y = dis[node] * sum;
    unsafeAtomicAdd(&gacc[loadi(batch, node, I64)], y);
}

// ---------------- k_head: out[g] = gacc[g]/cnt + cterm + bl -------------------
__global__ void k_head(const int* __restrict__ gptr, const float* __restrict__ gacc,
                       const float* __restrict__ w3l, const void* __restrict__ bl,
                       void* __restrict__ out, const int* __restrict__ flags) {
    int F32 = flags[0];
    int g = blockIdx.x * 256 + threadIdx.x;
    if (g >= N_GRAPHS) return;
    int cnt = gptr[g + 1] - gptr[g];
    float r = (cnt > 0) ? (gacc[g] / (float)cnt + w3l[64]) : 0.f;
    r += loadf(bl, 0, F32);
    if (F32) ((float*)out)[g] = r;
    else     ((__hip_bfloat16*)out)[g] = __float2bfloat16(r);
}

extern "C" void kernel_launch(void* const* d_in, const int* in_sizes, int n_in,
                              void* d_out, int out_size, void* d_ws, size_t ws_size,
                              hipStream_t stream) {
    const void* x     = d_in[0];
    const void* ei    = d_in[1];
    const void* batch = d_in[2];
    const void* W1 = d_in[3];
    const void* b1 = d_in[4];
    const void* W2 = d_in[5];
    const void* b2 = d_in[6];
    const void* W3 = d_in[7];
    const void* b3 = d_in[8];
    const void* Wl = d_in[9];
    const void* bl = d_in[10];

    // workspace layout (~42 MB)
    float* dis   = (float*)d_ws;             // 100352
    int2*  rp2   = (int2*)(dis + 100352);    // 100352 int2 (start,end)
    int*   csr   = (int*)(rp2 + 100352);     // NB*BCAP (per-bucket dense, 7.8 MB)
    int*   gcnt  = csr + NB * BCAP;          // 1024
    int*   gptr  = gcnt + 1024;              // 1056 (needs 1025)
    int*   bcnt  = gptr + 1056;              // 256
    int*   flags = bcnt + 256;               // 16
    float* w3l   = (float*)(flags + 16);     // 80 (w3l[64] = cterm)
    float* gacc  = w3l + 80;                 // 1024
    unsigned int* packed = (unsigned int*)(gacc + 1024);   // NB*BCAP (7.8 MB)
    float* z = (float*)packed;               // aliases packed (dead after k_csr)
    unsigned short* bufA = (unsigned short*)(packed + (size_t)NB * BCAP);  // 12.8 MB
    unsigned short* bufB = bufA + (size_t)N_NODES * 64;                    // 12.8 MB

    const int TB = 256;
    dim3 blk(TB);
    int gGA = 391 * 8;                       // layer-1 gather grid
    int gFG = (N_NODES + 63) / 64;           // 1563 fused-layer blocks

    // init: detect + w3l/cterm + zero counters/gacc
    k_init<<<1, blk, 0, stream>>>((const unsigned int*)x, (const unsigned int*)ei,
                                  flags, gcnt, bcnt, W3, b3, Wl, w3l, gacc);
    // phase A partition
    k_part<<<(N_EDGES + EPB - 1) / EPB, blk, 0, stream>>>(ei, batch, bcnt, gcnt, packed, flags);
    // fused CSR build + graph scan
    k_csr<<<NBU + 1, 512, 0, stream>>>(packed, bcnt, dis, rp2, csr, gcnt, gptr);

    // ---- layer 1: transform-first (128 -> 64), then gather -> hs1 node-major --
    k_gemm<F_IN><<<1024, blk, 0, stream>>>(x, W1, dis, bufA, flags, -1);
    k_gather_sm<<<gGA, blk, 0, stream>>>(rp2, csr, dis, bufA, b1, bufB, flags);
    // ---- layer 2: fused agg-first gather + GEMM -> hs2 (bufA) ----
    k_fgl<<<gFG, blk, 0, stream>>>(rp2, csr, dis, bufB, W2, b2, bufA, 1, flags);
    // ---- layer 3 + pool + head: scalarized via z = hs2 . (W3@Wl) ----
    k_z<<<N_NODES / 32, blk, 0, stream>>>(bufA, w3l, z);
    k_l3<<<(N_NODES + 255) / 256, blk, 0, stream>>>(rp2, csr, dis, z, batch, gacc, flags);
    k_head<<<(N_GRAPHS + 255) / 256, blk, 0, stream>>>(gptr, gacc, w3l, bl, d_out, flags);
}